// Round 3
// baseline (280.104 us; speedup 1.0000x reference)
//
#include <hip/hip_runtime.h>

#define B_SZ 32
#define D_CH 96
#define L_SZ 4096   // 64*64
#define N_ST 4
#define R_RK 6

static __device__ __forceinline__ float softplus_f(float v) {
    return fmaxf(v, 0.0f) + __logf(1.0f + __expf(-fabsf(v)));
}

// ---------------------------------------------------------------------------
// Kernel 1: depthwise 5x5 conv (pad=2) + bias + SiLU
// one block per (b,d); tile stride 72 (image at col offset 4 -> 16B aligned);
// thread = 1x16 horizontal strip; 6x ds_read_b128 per kernel row.
// ---------------------------------------------------------------------------
__global__ __launch_bounds__(256) void conv_silu_kernel(
    const float* __restrict__ x, const float* __restrict__ conv_w,
    const float* __restrict__ conv_b, float* __restrict__ xs)
{
    __shared__ float tile[68 * 72];   // rows 0..67, cols 0..71; pixel(gh,gw) at [gh+2][gw+4]
    const int t = threadIdx.x;
    const int bd = blockIdx.x;
    const int d = bd % D_CH;          // block-uniform -> weights via s_load
    const float* img = x + bd * L_SZ;

    float wreg[25];
#pragma unroll
    for (int i = 0; i < 25; ++i) wreg[i] = conv_w[d * 25 + i];
    const float bias = conv_b[d];

    const float4 z4 = make_float4(0.f, 0.f, 0.f, 0.f);
    for (int i = t; i < 68 * 72 / 4; i += 256) ((float4*)tile)[i] = z4;
    __syncthreads();
    // interior: 64 rows x 16 float4
    for (int i = t; i < 1024; i += 256) {
        const int r = i >> 4;
        const int c = (i & 15) << 2;
        const float4 v = *(const float4*)(img + (r << 6) + c);
        *(float4*)(tile + (r + 2) * 72 + 4 + c) = v;
    }
    __syncthreads();

    const int hr = t >> 2;            // output row 0..63
    const int cb = (t & 3) << 4;      // output col base 0,16,32,48

    float acc[16];
#pragma unroll
    for (int j = 0; j < 16; ++j) acc[j] = bias;

#pragma unroll
    for (int kh = 0; kh < 5; ++kh) {
        const float* rp = tile + (hr + kh) * 72 + cb;
        float r24[24];
#pragma unroll
        for (int q = 0; q < 6; ++q) {
            const float4 v = ((const float4*)rp)[q];
            r24[4*q+0] = v.x; r24[4*q+1] = v.y; r24[4*q+2] = v.z; r24[4*q+3] = v.w;
        }
#pragma unroll
        for (int j = 0; j < 16; ++j)
#pragma unroll
            for (int kw = 0; kw < 5; ++kw)
                acc[j] += wreg[kh * 5 + kw] * r24[j + kw + 2];
    }

    float* out = xs + bd * L_SZ + (hr << 6) + cb;
#pragma unroll
    for (int q = 0; q < 4; ++q) {
        float4 v;
#pragma unroll
        for (int j = 0; j < 4; ++j) {
            const float a = acc[4*q + j];
            const float s = __builtin_amdgcn_rcpf(1.0f + __expf(-a));
            (&v.x)[j] = a * s;
        }
        ((float4*)out)[q] = v;
    }
}

// ---------------------------------------------------------------------------
// Kernel 2: x_dbl[b,k,l] = sum_d x_proj_w[k,d] * xs[b,d,l]
// block = (b, 64-l chunk); 256 thr = 4 d-groups x 64 lanes; LDS reduce.
// ---------------------------------------------------------------------------
__global__ __launch_bounds__(256) void proj_kernel(
    const float* __restrict__ xs, const float* __restrict__ x_proj_w,
    float* __restrict__ x_dbl)
{
    __shared__ float red[4][14][64];
    const int t = threadIdx.x;
    const int g = t >> 6;
    const int ll = t & 63;
    const int bi = blockIdx.x;
    const int b = bi >> 6;
    const int chunk = bi & 63;
    const int l = (chunk << 6) + ll;
    const int d0 = __builtin_amdgcn_readfirstlane(g * 24);   // wave-uniform -> s_load weights

    const float* xsb = xs + (b * D_CH + d0) * L_SZ + l;
    float acc[14];
#pragma unroll
    for (int k = 0; k < 14; ++k) acc[k] = 0.0f;

#pragma unroll
    for (int dd = 0; dd < 24; ++dd) {
        const float xv = xsb[dd * L_SZ];
#pragma unroll
        for (int k = 0; k < 14; ++k)
            acc[k] += x_proj_w[k * D_CH + d0 + dd] * xv;
    }

#pragma unroll
    for (int k = 0; k < 14; ++k) red[g][k][ll] = acc[k];
    __syncthreads();

    float* outb = x_dbl + b * 14 * L_SZ + (chunk << 6);
    for (int i = t; i < 14 * 64; i += 256) {
        const int k = i >> 6;
        const int c = i & 63;
        outb[k * L_SZ + c] = red[0][k][c] + red[1][k][c] + red[2][k][c] + red[3][k][c];
    }
}

// ---------------------------------------------------------------------------
// block exclusive scan (256 thr, 4 waves), ONE barrier, disjoint LDS slot
// ---------------------------------------------------------------------------
static __device__ __forceinline__ float block_excl_scan(float v, float* slot, int t)
{
    const int lane = t & 63;
    const int wid = t >> 6;
    float incl = v;
#pragma unroll
    for (int off = 1; off < 64; off <<= 1) {
        const float u = __shfl_up(incl, (unsigned)off, 64);
        if (lane >= off) incl += u;
    }
    if (lane == 63) slot[wid] = incl;
    float ex = __shfl_up(incl, 1u, 64);
    if (lane == 0) ex = 0.0f;
    __syncthreads();
    float wp = 0.0f;
    if (wid > 0) wp += slot[0];
    if (wid > 1) wp += slot[1];
    if (wid > 2) wp += slot[2];
    return wp + ex;
}

// ---------------------------------------------------------------------------
// Kernel 3: selective scan (reference cumsum-trick, exact formulation)
// one block per (b,d); 256 threads x 16 contiguous l each.
// P = rcp(exp(-S)) (S<=0 so exp(-S)>=1); pinv = min(exp(-S),1e9)
// ---------------------------------------------------------------------------
__global__ __launch_bounds__(256, 4) void scan_kernel(
    const float* __restrict__ xs, const float* __restrict__ x_dbl,
    const float* __restrict__ dt_w, const float* __restrict__ dt_b,
    const float* __restrict__ A_logs, const float* __restrict__ Ds,
    float* __restrict__ y)
{
    constexpr float LOG_EPS_F = -20.723265836946414f;  // ln(1e-9)

    __shared__ float slots[8][4];     // one 4-entry slot per scan call
    const int t = threadIdx.x;
    const int bd = blockIdx.x;
    const int b = bd / D_CH;
    const int d = bd - b * D_CH;
    const int l0 = t * 16;

    const float* xs_row = xs + bd * L_SZ + l0;
    const float* xd = x_dbl + b * 14 * L_SZ + l0;

    float xv[16], dl[16], yac[16];
#pragma unroll
    for (int i = 0; i < 4; ++i) {
        const float4 v = ((const float4*)xs_row)[i];
        xv[4*i+0] = v.x; xv[4*i+1] = v.y; xv[4*i+2] = v.z; xv[4*i+3] = v.w;
    }

    const float dtb = dt_b[d];
#pragma unroll
    for (int i = 0; i < 16; ++i) { dl[i] = dtb; yac[i] = 0.0f; }
#pragma unroll
    for (int r = 0; r < R_RK; ++r) {
        const float wr = dt_w[d * R_RK + r];          // uniform -> s_load
        const float* row = xd + r * L_SZ;
#pragma unroll
        for (int i = 0; i < 4; ++i) {
            const float4 v = ((const float4*)row)[i];
            dl[4*i+0] += wr * v.x; dl[4*i+1] += wr * v.y;
            dl[4*i+2] += wr * v.z; dl[4*i+3] += wr * v.w;
        }
    }
#pragma unroll
    for (int i = 0; i < 16; ++i) dl[i] = softplus_f(dl[i]);

#pragma unroll
    for (int n = 0; n < N_ST; ++n) {
        const float An = -__expf(A_logs[d * N_ST + n]);  // uniform

        // ---- local cumsum of log_dA -> SP holds S ----
        float SP[16];
        float run = 0.0f;
#pragma unroll
        for (int i = 0; i < 16; ++i) {
            run += fmaxf(dl[i] * An, LOG_EPS_F);
            SP[i] = run;
        }
        const float ex1 = block_excl_scan(run, slots[2*n], t);

        // ---- cumsum of dB_u * pinv; SP becomes P ----
        const float* Brow = xd + (R_RK + n) * L_SZ;
        float carr[16];
        float run2 = 0.0f;
#pragma unroll
        for (int i = 0; i < 4; ++i) {
            const float4 v = ((const float4*)Brow)[i];
            const float bb[4] = {v.x, v.y, v.z, v.w};
#pragma unroll
            for (int j = 0; j < 4; ++j) {
                const int idx = 4*i + j;
                const float S = SP[idx] + ex1;
                const float e = __expf(-S);              // >= 1
                const float pinv = fminf(e, 1e9f);
                SP[idx] = __builtin_amdgcn_rcpf(e);      // = exp(S)
                run2 += dl[idx] * bb[j] * xv[idx] * pinv;
                carr[idx] = run2;
            }
        }
        const float ex2 = block_excl_scan(run2, slots[2*n+1], t);

        const float* Crow = xd + (R_RK + N_ST + n) * L_SZ;
#pragma unroll
        for (int i = 0; i < 4; ++i) {
            const float4 v = ((const float4*)Crow)[i];
            const float cc[4] = {v.x, v.y, v.z, v.w};
#pragma unroll
            for (int j = 0; j < 4; ++j) {
                const int idx = 4*i + j;
                yac[idx] += (SP[idx] * (carr[idx] + ex2)) * cc[j];
            }
        }
    }

    const float dsd = Ds[d];
    float* yrow = y + bd * L_SZ + l0;
#pragma unroll
    for (int i = 0; i < 4; ++i) {
        float4 v;
        v.x = yac[4*i+0] + xv[4*i+0] * dsd;
        v.y = yac[4*i+1] + xv[4*i+1] * dsd;
        v.z = yac[4*i+2] + xv[4*i+2] * dsd;
        v.w = yac[4*i+3] + xv[4*i+3] * dsd;
        ((float4*)yrow)[i] = v;
    }
}

// ---------------------------------------------------------------------------
extern "C" void kernel_launch(void* const* d_in, const int* in_sizes, int n_in,
                              void* d_out, int out_size, void* d_ws, size_t ws_size,
                              hipStream_t stream)
{
    const float* x        = (const float*)d_in[0];
    const float* conv_w   = (const float*)d_in[1];
    const float* conv_b   = (const float*)d_in[2];
    const float* x_proj_w = (const float*)d_in[3];
    const float* dt_w     = (const float*)d_in[4];
    const float* dt_b     = (const float*)d_in[5];
    const float* A_logs   = (const float*)d_in[6];
    const float* Ds       = (const float*)d_in[7];

    float* y     = (float*)d_out;
    float* xs    = y;                 // stage conv output in d_out; scan reads
                                      // and overwrites it thread-privately
    float* x_dbl = (float*)d_ws;      // 32*14*4096 floats = 7.34 MB

    conv_silu_kernel<<<B_SZ * D_CH, 256, 0, stream>>>(x, conv_w, conv_b, xs);
    proj_kernel<<<B_SZ * 64, 256, 0, stream>>>(xs, x_proj_w, x_dbl);
    scan_kernel<<<B_SZ * D_CH, 256, 0, stream>>>(xs, x_dbl, dt_w, dt_b,
                                                 A_logs, Ds, y);
}

// Round 4
// 178.594 us; speedup vs baseline: 1.5684x; 1.5684x over previous
//
#include <hip/hip_runtime.h>

#define B_SZ 32
#define D_CH 96
#define L_SZ 4096   // 64*64
#define N_ST 4
#define R_RK 6

static __device__ __forceinline__ float softplus_f(float v) {
    return fmaxf(v, 0.0f) + __logf(1.0f + __expf(-fabsf(v)));
}

// ---------------------------------------------------------------------------
// Kernel 1: depthwise 5x5 conv (pad=2) + bias + SiLU
// one block per (b,d); tile stride 76 floats (=12 mod 32 banks: spreads the
// per-wave row pattern; 72 gave 8-way first-dword conflicts);
// thread = 1x16 horizontal strip; 6x ds_read_b128 per kernel row.
// ---------------------------------------------------------------------------
#define TS 76
__global__ __launch_bounds__(256) void conv_silu_kernel(
    const float* __restrict__ x, const float* __restrict__ conv_w,
    const float* __restrict__ conv_b, float* __restrict__ xs)
{
    __shared__ float tile[68 * TS];   // pixel(gh,gw) at [gh+2][gw+4]
    const int t = threadIdx.x;
    const int bd = blockIdx.x;
    const int d = bd % D_CH;          // block-uniform -> weights via s_load
    const float* img = x + bd * L_SZ;

    float wreg[25];
#pragma unroll
    for (int i = 0; i < 25; ++i) wreg[i] = conv_w[d * 25 + i];
    const float bias = conv_b[d];

    const float4 z4 = make_float4(0.f, 0.f, 0.f, 0.f);
    for (int i = t; i < 68 * TS / 4; i += 256) ((float4*)tile)[i] = z4;
    __syncthreads();
    // interior: 64 rows x 16 float4
    for (int i = t; i < 1024; i += 256) {
        const int r = i >> 4;
        const int c = (i & 15) << 2;
        const float4 v = *(const float4*)(img + (r << 6) + c);
        *(float4*)(tile + (r + 2) * TS + 4 + c) = v;
    }
    __syncthreads();

    const int hr = t >> 2;            // output row 0..63
    const int cb = (t & 3) << 4;      // output col base 0,16,32,48

    float acc[16];
#pragma unroll
    for (int j = 0; j < 16; ++j) acc[j] = bias;

#pragma unroll
    for (int kh = 0; kh < 5; ++kh) {
        const float* rp = tile + (hr + kh) * TS + cb;
        float r24[24];
#pragma unroll
        for (int q = 0; q < 6; ++q) {
            const float4 v = ((const float4*)rp)[q];
            r24[4*q+0] = v.x; r24[4*q+1] = v.y; r24[4*q+2] = v.z; r24[4*q+3] = v.w;
        }
#pragma unroll
        for (int j = 0; j < 16; ++j)
#pragma unroll
            for (int kw = 0; kw < 5; ++kw)
                acc[j] += wreg[kh * 5 + kw] * r24[j + kw + 2];
    }

    float* out = xs + bd * L_SZ + (hr << 6) + cb;
#pragma unroll
    for (int q = 0; q < 4; ++q) {
        float4 v;
#pragma unroll
        for (int j = 0; j < 4; ++j) {
            const float a = acc[4*q + j];
            const float s = __builtin_amdgcn_rcpf(1.0f + __expf(-a));
            (&v.x)[j] = a * s;
        }
        ((float4*)out)[q] = v;
    }
}

// ---------------------------------------------------------------------------
// Kernel 2: x_dbl[b,k,l] = sum_d x_proj_w[k,d] * xs[b,d,l]
// block = (b, 64-l chunk); 256 thr = 4 d-groups x 64 lanes; LDS reduce.
// ---------------------------------------------------------------------------
__global__ __launch_bounds__(256) void proj_kernel(
    const float* __restrict__ xs, const float* __restrict__ x_proj_w,
    float* __restrict__ x_dbl)
{
    __shared__ float red[4][14][64];
    const int t = threadIdx.x;
    const int g = t >> 6;
    const int ll = t & 63;
    const int bi = blockIdx.x;
    const int b = bi >> 6;
    const int chunk = bi & 63;
    const int l = (chunk << 6) + ll;
    const int d0 = __builtin_amdgcn_readfirstlane(g * 24);   // wave-uniform -> s_load weights

    const float* xsb = xs + (b * D_CH + d0) * L_SZ + l;
    float acc[14];
#pragma unroll
    for (int k = 0; k < 14; ++k) acc[k] = 0.0f;

#pragma unroll
    for (int dd = 0; dd < 24; ++dd) {
        const float xv = xsb[dd * L_SZ];
#pragma unroll
        for (int k = 0; k < 14; ++k)
            acc[k] += x_proj_w[k * D_CH + d0 + dd] * xv;
    }

#pragma unroll
    for (int k = 0; k < 14; ++k) red[g][k][ll] = acc[k];
    __syncthreads();

    float* outb = x_dbl + b * 14 * L_SZ + (chunk << 6);
    for (int i = t; i < 14 * 64; i += 256) {
        const int k = i >> 6;
        const int c = i & 63;
        outb[k * L_SZ + c] = red[0][k][c] + red[1][k][c] + red[2][k][c] + red[3][k][c];
    }
}

// ---------------------------------------------------------------------------
// block exclusive scan (512 thr, 8 waves), ONE barrier, disjoint LDS slot
// ---------------------------------------------------------------------------
static __device__ __forceinline__ float block_excl_scan(float v, float* slot, int t)
{
    const int lane = t & 63;
    const int wid = t >> 6;
    float incl = v;
#pragma unroll
    for (int off = 1; off < 64; off <<= 1) {
        const float u = __shfl_up(incl, (unsigned)off, 64);
        if (lane >= off) incl += u;
    }
    if (lane == 63) slot[wid] = incl;
    float ex = __shfl_up(incl, 1u, 64);
    if (lane == 0) ex = 0.0f;
    __syncthreads();
    float wp = 0.0f;
#pragma unroll
    for (int w = 0; w < 7; ++w)
        if (w < wid) wp += slot[w];
    return wp + ex;
}

// ---------------------------------------------------------------------------
// Kernel 3: selective scan (reference cumsum-trick, exact formulation)
// one block per (b,d); 512 threads x 8 contiguous l each.
// no divides: 1/max(P,EPS) == min(exp(-S),1e9); P = rcp(exp(-S))
// ---------------------------------------------------------------------------
__global__ __launch_bounds__(512, 4) void scan_kernel(
    const float* __restrict__ xs, const float* __restrict__ x_dbl,
    const float* __restrict__ dt_w, const float* __restrict__ dt_b,
    const float* __restrict__ A_logs, const float* __restrict__ Ds,
    float* __restrict__ y)
{
    constexpr float LOG_EPS_F = -20.723265836946414f;  // ln(1e-9)

    __shared__ float slots[8][8];     // one 8-entry slot per block-scan call
    const int t = threadIdx.x;
    const int bd = blockIdx.x;
    const int b = bd / D_CH;
    const int d = bd - b * D_CH;
    const int l0 = t * 8;

    const float* xs_row = xs + bd * L_SZ + l0;
    const float* xd = x_dbl + b * 14 * L_SZ + l0;

    float xv[8], dl[8], yac[8];
#pragma unroll
    for (int i = 0; i < 2; ++i) {
        const float4 v = ((const float4*)xs_row)[i];
        xv[4*i+0] = v.x; xv[4*i+1] = v.y; xv[4*i+2] = v.z; xv[4*i+3] = v.w;
    }

    const float dtb = dt_b[d];
#pragma unroll
    for (int i = 0; i < 8; ++i) { dl[i] = dtb; yac[i] = 0.0f; }
#pragma unroll
    for (int r = 0; r < R_RK; ++r) {
        const float wr = dt_w[d * R_RK + r];          // uniform -> s_load
        const float* row = xd + r * L_SZ;
#pragma unroll
        for (int i = 0; i < 2; ++i) {
            const float4 v = ((const float4*)row)[i];
            dl[4*i+0] += wr * v.x; dl[4*i+1] += wr * v.y;
            dl[4*i+2] += wr * v.z; dl[4*i+3] += wr * v.w;
        }
    }
#pragma unroll
    for (int i = 0; i < 8; ++i) dl[i] = softplus_f(dl[i]);

    for (int n = 0; n < N_ST; ++n) {
        const float An = -__expf(A_logs[d * N_ST + n]);  // uniform

        // ---- local cumsum of log_dA -> SP holds S ----
        float SP[8];
        float run = 0.0f;
#pragma unroll
        for (int i = 0; i < 8; ++i) {
            run += fmaxf(dl[i] * An, LOG_EPS_F);
            SP[i] = run;
        }
        const float ex1 = block_excl_scan(run, slots[2*n], t);

        // ---- cumsum of dB_u * pinv; SP becomes P ----
        const float* Brow = xd + (R_RK + n) * L_SZ;
        float carr[8];
        float run2 = 0.0f;
#pragma unroll
        for (int i = 0; i < 2; ++i) {
            const float4 v = ((const float4*)Brow)[i];
            const float bb[4] = {v.x, v.y, v.z, v.w};
#pragma unroll
            for (int j = 0; j < 4; ++j) {
                const int idx = 4*i + j;
                const float S = SP[idx] + ex1;
                const float e = __expf(-S);              // >= 1
                const float pinv = fminf(e, 1e9f);
                SP[idx] = __builtin_amdgcn_rcpf(e);      // = exp(S)
                run2 += dl[idx] * bb[j] * xv[idx] * pinv;
                carr[idx] = run2;
            }
        }
        const float ex2 = block_excl_scan(run2, slots[2*n+1], t);

        const float* Crow = xd + (R_RK + N_ST + n) * L_SZ;
#pragma unroll
        for (int i = 0; i < 2; ++i) {
            const float4 v = ((const float4*)Crow)[i];
            const float cc[4] = {v.x, v.y, v.z, v.w};
#pragma unroll
            for (int j = 0; j < 4; ++j) {
                const int idx = 4*i + j;
                yac[idx] += (SP[idx] * (carr[idx] + ex2)) * cc[j];
            }
        }
    }

    const float dsd = Ds[d];
    float* yrow = y + bd * L_SZ + l0;
#pragma unroll
    for (int i = 0; i < 2; ++i) {
        float4 v;
        v.x = yac[4*i+0] + xv[4*i+0] * dsd;
        v.y = yac[4*i+1] + xv[4*i+1] * dsd;
        v.z = yac[4*i+2] + xv[4*i+2] * dsd;
        v.w = yac[4*i+3] + xv[4*i+3] * dsd;
        ((float4*)yrow)[i] = v;
    }
}

// ---------------------------------------------------------------------------
extern "C" void kernel_launch(void* const* d_in, const int* in_sizes, int n_in,
                              void* d_out, int out_size, void* d_ws, size_t ws_size,
                              hipStream_t stream)
{
    const float* x        = (const float*)d_in[0];
    const float* conv_w   = (const float*)d_in[1];
    const float* conv_b   = (const float*)d_in[2];
    const float* x_proj_w = (const float*)d_in[3];
    const float* dt_w     = (const float*)d_in[4];
    const float* dt_b     = (const float*)d_in[5];
    const float* A_logs   = (const float*)d_in[6];
    const float* Ds       = (const float*)d_in[7];

    float* y     = (float*)d_out;
    float* xs    = y;                 // stage conv output in d_out; scan reads
                                      // and overwrites it thread-privately
    float* x_dbl = (float*)d_ws;      // 32*14*4096 floats = 7.34 MB

    conv_silu_kernel<<<B_SZ * D_CH, 256, 0, stream>>>(x, conv_w, conv_b, xs);
    proj_kernel<<<B_SZ * 64, 256, 0, stream>>>(xs, x_proj_w, x_dbl);
    scan_kernel<<<B_SZ * D_CH, 512, 0, stream>>>(xs, x_dbl, dt_w, dt_b,
                                                 A_logs, Ds, y);
}